// Round 19
// baseline (209.309 us; speedup 1.0000x reference)
//
#include <hip/hip_runtime.h>
#include <hip/hip_bf16.h>
#include <stdint.h>
#include <stddef.h>

typedef short short8 __attribute__((ext_vector_type(8)));
typedef float f32x4 __attribute__((ext_vector_type(4)));
typedef unsigned short bf16x4 __attribute__((ext_vector_type(4)));

#define SROWS 65536
#define TROWS 8192
#define HDIM  1024
#define KDIM  2048   // concatenated K: [edu | h]
#define NT    32     // K-tiles of 64
#define BUF   40960  // per-buffer LDS: A 16K + Brz 16K + Bn 8K

__device__ __forceinline__ unsigned short f2bf(float f) {
  union { float f; uint32_t u; } v; v.f = f;
  uint32_t u = v.u;
  uint32_t r = (u + 0x7FFFu + ((u >> 16) & 1u)) >> 16;
  return (unsigned short)r;
}

__device__ __forceinline__ float bf2f(unsigned short b) {
  union { uint32_t u; float f; } v; v.u = ((uint32_t)b) << 16;
  return v.f;
}

__device__ __forceinline__ float fast_sigmoid(float x) {
  return __builtin_amdgcn_rcpf(1.0f + __builtin_amdgcn_exp2f(-1.44269504f * x));
}
__device__ __forceinline__ float fast_tanh(float x) {
  return 1.0f - 2.0f * __builtin_amdgcn_rcpf(1.0f + __builtin_amdgcn_exp2f(2.88539008f * x));
}

// ---------------- merged prep kernels ----------------

// lp init (65536) + bias table (first 1024 threads)
__global__ __launch_bounds__(256) void k_init(int* lp,
                                              const float* __restrict__ bih,
                                              const float* __restrict__ bhh,
                                              float* __restrict__ btab) {
  int i = blockIdx.x * 256 + threadIdx.x;
  lp[i] = -1;
  if (i < HDIM) {
    btab[4*i+0] = bih[i] + bhh[i];
    btab[4*i+1] = bih[i+HDIM] + bhh[i+HDIM];
    btab[4*i+2] = bih[i+2*HDIM];
    btab[4*i+3] = bhh[i+2*HDIM];
  }
}

__global__ __launch_bounds__(256) void k_lp(const int* __restrict__ sid, int* lp) {
  int i = blockIdx.x * 256 + threadIdx.x;
  if (i < TROWS) atomicMax(&lp[sid[i]], i);
}

// per-row "untouched" bitmask: bit r of flagb[r>>6] = (lp[r] < 0)
__global__ __launch_bounds__(256) void k_flags(const int* __restrict__ lp,
                                               unsigned long long* __restrict__ flagb) {
  int i = blockIdx.x * 256 + threadIdx.x;
  unsigned long long m = __ballot(lp[i] < 0);
  if ((threadIdx.x & 63) == 0) flagb[i >> 6] = m;
}

// merged build_A (blocks 0..8191) + build_B2 (blocks 8192..11263)
__global__ __launch_bounds__(256) void k_build(const float* __restrict__ edu,
                                               const float* __restrict__ mem,
                                               const int* __restrict__ sid,
                                               const float* __restrict__ Wih,
                                               const float* __restrict__ Whh,
                                               unsigned short* __restrict__ Ac,
                                               unsigned short* __restrict__ Brz,
                                               unsigned short* __restrict__ Bn) {
  const int b = blockIdx.x;
  if (b < 8192) {
    const int idx = b * 256 + threadIdx.x;
    const int t  = idx >> 8;
    const int k0 = (idx & 255) << 3;
    const float* src;
    if (k0 < HDIM) src = edu + (size_t)t * HDIM + k0;
    else           src = mem + (size_t)sid[t] * HDIM + (k0 - HDIM);
    f32x4 f0 = *(const f32x4*)src;
    f32x4 f1 = *(const f32x4*)(src + 4);
    short8 v;
    v[0]=(short)f2bf(f0[0]); v[1]=(short)f2bf(f0[1]); v[2]=(short)f2bf(f0[2]); v[3]=(short)f2bf(f0[3]);
    v[4]=(short)f2bf(f1[0]); v[5]=(short)f2bf(f1[1]); v[6]=(short)f2bf(f1[2]); v[7]=(short)f2bf(f1[3]);
    *(short8*)(Ac + (size_t)idx * 8) = v;
  } else {
    const int idx = (b - 8192) * 256 + threadIdx.x;
    const int c  = idx >> 8;
    const int k0 = (idx & 255) << 3;
    const float* src;
    unsigned short* dst;
    if (c < 2048) {
      const int j = c >> 1, g = c & 1;
      const int row = j + g * 1024;
      src = (k0 < HDIM) ? Wih + (size_t)row * HDIM + k0
                        : Whh + (size_t)row * HDIM + (k0 - HDIM);
      dst = Brz + (size_t)c * KDIM + k0;
    } else {
      const int j = c - 2048;
      src = (k0 < HDIM) ? Wih + (size_t)(j + 2*HDIM) * HDIM + k0
                        : Whh + (size_t)(j + 2*HDIM) * HDIM + (k0 - HDIM);
      dst = Bn + (size_t)j * KDIM + k0;
    }
    f32x4 f0 = *(const f32x4*)src;
    f32x4 f1 = *(const f32x4*)(src + 4);
    short8 v;
    v[0]=(short)f2bf(f0[0]); v[1]=(short)f2bf(f0[1]); v[2]=(short)f2bf(f0[2]); v[3]=(short)f2bf(f0[3]);
    v[4]=(short)f2bf(f1[0]); v[5]=(short)f2bf(f1[1]); v[6]=(short)f2bf(f1[2]); v[7]=(short)f2bf(f1[3]);
    *(short8*)dst = v;
  }
}

// ---------------- 128x64j dense GEMM, 2 blocks/CU, 2 barriers/tile ----------------
// r17's best-known GEMM; only change: epilogue h read from Ac (bf16, L2-warm)
// instead of the scattered f32 mem gather (-32MB HBM).

#define FENCE() asm volatile("" ::: "memory")
#define BAR()   __builtin_amdgcn_s_barrier()
#define VM(N)   asm volatile("s_waitcnt vmcnt(" #N ")" ::: "memory")

#define STAGE(p0, p1, ldsoff)                                                              \
  __builtin_amdgcn_global_load_lds((const __attribute__((address_space(1))) void*)(p0),   \
      (__attribute__((address_space(3))) void*)(smem + (ldsoff) + w * 1024), 16, 0, 0);    \
  __builtin_amdgcn_global_load_lds((const __attribute__((address_space(1))) void*)(p1),   \
      (__attribute__((address_space(3))) void*)(smem + (ldsoff) + 8192 + w * 1024), 16, 0, 0);

#define STAGE1(p0, ldsoff)                                                                 \
  __builtin_amdgcn_global_load_lds((const __attribute__((address_space(1))) void*)(p0),   \
      (__attribute__((address_space(3))) void*)(smem + (ldsoff) + w * 1024), 16, 0, 0);

#define LDF(base, frag, koff) (*(const short8*)(smem + (base) + (size_t)(frag) * 2048 + (koff)))

#define MF(a, b, c) __builtin_amdgcn_mfma_f32_16x16x32_bf16(a, b, c, 0, 0, 0)

#define MFMA12(ACCN)                                                          \
    acc_rz[0][0] = MF(af[0], bf0, acc_rz[0][0]);                              \
    acc_rz[0][1] = MF(af[0], bf1, acc_rz[0][1]);                              \
    ACCN[0]      = MF(af[0], bf2, ACCN[0]);                                   \
    acc_rz[1][0] = MF(af[1], bf0, acc_rz[1][0]);                              \
    acc_rz[1][1] = MF(af[1], bf1, acc_rz[1][1]);                              \
    ACCN[1]      = MF(af[1], bf2, ACCN[1]);                                   \
    acc_rz[2][0] = MF(af[2], bf0, acc_rz[2][0]);                              \
    acc_rz[2][1] = MF(af[2], bf1, acc_rz[2][1]);                              \
    ACCN[2]      = MF(af[2], bf2, ACCN[2]);                                   \
    acc_rz[3][0] = MF(af[3], bf0, acc_rz[3][0]);                              \
    acc_rz[3][1] = MF(af[3], bf1, acc_rz[3][1]);                              \
    ACCN[3]      = MF(af[3], bf2, ACCN[3]);

#define TILE_BODY(ACCN)                                                       \
  {                                                                           \
    const int cur = t & 1;                                                    \
    const size_t buf = (size_t)cur * BUF, nbuf = (size_t)(cur ^ 1) * BUF;     \
    const size_t abase  = buf + (size_t)wm * 8192;                            \
    const size_t rzbase = buf + 16384 + (size_t)wn * 4096;                    \
    const size_t nbase  = buf + 32768 + (size_t)wn * 2048;                    \
    const int kt1 = (t + 1 < NT) ? t + 1 : NT - 1;                            \
    /* ph0: stage t+1 -> nbuf; retire ONLY stages(t); keep copy loads */      \
    STAGE(pA0 + kt1 * 64, pA1 + kt1 * 64, nbuf);                              \
    STAGE(pRZ0 + kt1 * 64, pRZ1 + kt1 * 64, nbuf + 16384);                    \
    STAGE1(pN + kt1 * 64, nbuf + 32768);                                      \
    VM(7);                                                                    \
    FENCE(); BAR(); FENCE();                                                  \
    {                                                                         \
      short8 bf0 = LDF(rzbase, 0, foff0);                                     \
      short8 bf1 = LDF(rzbase, 1, foff0);                                     \
      short8 bf2 = LDF(nbase,  0, foff0);                                     \
      short8 af[4];                                                           \
      af[0] = LDF(abase, 0, foff0); af[1] = LDF(abase, 1, foff0);             \
      af[2] = LDF(abase, 2, foff0); af[3] = LDF(abase, 3, foff0);             \
      __builtin_amdgcn_s_setprio(1);                                          \
      MFMA12(ACCN)                                                            \
      __builtin_amdgcn_s_setprio(0);                                          \
    }                                                                         \
    /* ph1: compute k1, retire copy-loads(t-1), store them, issue copies(t) */\
    {                                                                         \
      short8 bf0 = LDF(rzbase, 0, foff1);                                     \
      short8 bf1 = LDF(rzbase, 1, foff1);                                     \
      short8 bf2 = LDF(nbase,  0, foff1);                                     \
      short8 af[4];                                                           \
      af[0] = LDF(abase, 0, foff1); af[1] = LDF(abase, 1, foff1);             \
      af[2] = LDF(abase, 2, foff1); af[3] = LDF(abase, 3, foff1);             \
      __builtin_amdgcn_s_setprio(1);                                          \
      MFMA12(ACCN)                                                            \
      __builtin_amdgcn_s_setprio(0);                                          \
    }                                                                         \
    VM(5);                                                                    \
    {                                                                         \
      const int rr = 2 * t + ccp;                                             \
      const bool nv = (fw >> rr) & 1ull;                                      \
      if ((t & 1) == 0) {                                                     \
        if (vY) __builtin_nontemporal_store(cpY, (f32x4*)&out[(size_t)sY * HDIM + ccol]); \
        vX = nv; sX = cbase + rr;                                             \
        if (vX) cpX = __builtin_nontemporal_load((const f32x4*)&mem[(size_t)sX * HDIM + ccol]); \
      } else {                                                                \
        if (vX) __builtin_nontemporal_store(cpX, (f32x4*)&out[(size_t)sX * HDIM + ccol]); \
        vY = nv; sY = cbase + rr;                                             \
        if (vY) cpY = __builtin_nontemporal_load((const f32x4*)&mem[(size_t)sY * HDIM + ccol]); \
      }                                                                       \
    }                                                                         \
    FENCE(); BAR(); FENCE();                                                  \
  }

__global__ __launch_bounds__(512, 4)
void k_gru8(const unsigned short* __restrict__ Ac,
            const unsigned short* __restrict__ Brz,
            const unsigned short* __restrict__ Bn,
            const float* __restrict__ mem,
            const int* __restrict__ sid,
            const int* __restrict__ lp,
            const unsigned long long* __restrict__ flagb,
            const float* __restrict__ btab,
            float* __restrict__ out) {
  extern __shared__ char smem[];

  const int tid  = threadIdx.x;
  const int lane = tid & 63;
  const int w    = tid >> 6;
  const int wm   = w >> 2;        // M half (0..1): 64 rows
  const int wn   = w & 3;         // N quarter (0..3): 16 j's
  const int l15  = lane & 15;
  const int l4   = lane >> 4;

  // XCD-pinned j0 mapping (bijective)
  const int bid = blockIdx.x;
  const int t0  = (bid >> 4) * 128;                        // 64 M-panels
  const int j0  = ((bid & 7) * 2 + ((bid >> 3) & 1)) * 64; // 16 J-panels
  const int rz0 = j0 * 2;

  // ---- staging source mapping (inverse (row&7)<<4 swizzle folded in) ----
  const int srow0 = tid >> 3;              // 0..63
  const int scol  = ((tid & 7) * 8) ^ (((tid >> 3) & 7) << 3);

  const unsigned short* pA0  = Ac  + (size_t)(t0 +       srow0) * KDIM + scol;
  const unsigned short* pA1  = Ac  + (size_t)(t0 + 64 +  srow0) * KDIM + scol;
  const unsigned short* pRZ0 = Brz + (size_t)(rz0 +      srow0) * KDIM + scol;
  const unsigned short* pRZ1 = Brz + (size_t)(rz0 + 64 + srow0) * KDIM + scol;
  const unsigned short* pN   = Bn  + (size_t)(j0  +      srow0) * KDIM + scol;

  // ---- fragment read offsets: col_byte ^= (row&7)<<4 ----
  const int rsw = (l15 & 7) << 4;
  const size_t foff0 = (size_t)l15 * 128 + ((l4 * 16)      ^ rsw);
  const size_t foff1 = (size_t)l15 * 128 + ((64 + l4 * 16) ^ rsw);

  f32x4 acc_rz[4][2], acc_nlo[4], acc_nhi[4];
#pragma unroll
  for (int i = 0; i < 4; i++) {
    acc_rz[i][0] = (f32x4){0.f,0.f,0.f,0.f};
    acc_rz[i][1] = (f32x4){0.f,0.f,0.f,0.f};
    acc_nlo[i]   = (f32x4){0.f,0.f,0.f,0.f};
    acc_nhi[i]   = (f32x4){0.f,0.f,0.f,0.f};
  }

  // ---- copy state: 64 rows/block, 2/tile ----
  const int cbase = bid << 6;
  const unsigned long long fw = flagb[bid];
  const int ccp  = tid >> 8;               // 0/1 (wave-uniform)
  const int ccol = (tid & 255) << 2;
  f32x4 cpX, cpY;
  bool  vX = false, vY = false;
  int   sX = 0, sY = 0;

  // ---- prologue: stage tile 0 into buf0, full drain once
  STAGE(pA0, pA1, 0);
  STAGE(pRZ0, pRZ1, 16384);
  STAGE1(pN, 32768);
  VM(0);
  FENCE(); BAR(); FENCE();

  for (int t = 0; t < 16; ++t) TILE_BODY(acc_nlo)     // k < 1024: i_n
  for (int t = 16; t < NT; ++t) TILE_BODY(acc_nhi)    // k >= 1024: h_n

  // ---- drain: final copy store (t=31 odd -> set Y pending), then epilogue
  VM(0);
  if (vY) __builtin_nontemporal_store(cpY, (f32x4*)&out[(size_t)sY * HDIM + ccol]);
  __syncthreads();
  float* epi = (float*)smem;   // [8 waves][16 rows][68]
  const int jfirst = j0 + wn * 16 + l4 * 4;

#pragma unroll
  for (int mf = 0; mf < 4; mf++) {
#pragma unroll
    for (int f = 0; f < 2; f++)
#pragma unroll
      for (int r = 0; r < 4; r++)
        epi[w * 1088 + (l4 * 4 + r) * 68 + (f * 8 + (l15 >> 1)) * 4 + (l15 & 1)] = acc_rz[mf][f][r];
#pragma unroll
    for (int r = 0; r < 4; r++) {
      epi[w * 1088 + (l4 * 4 + r) * 68 + l15 * 4 + 2] = acc_nlo[mf][r];
      epi[w * 1088 + (l4 * 4 + r) * 68 + l15 * 4 + 3] = acc_nhi[mf][r];
    }
    __syncthreads();

    const int trow = t0 + wm * 64 + mf * 16 + l15;
    const int s    = sid[trow];
    const bool wr  = (lp[s] == trow);

    f32x4 q[4];
#pragma unroll
    for (int jj = 0; jj < 4; jj++)
      q[jj] = *(const f32x4*)&epi[w * 1088 + l15 * 68 + l4 * 16 + jj * 4];

    // h from Ac (bf16, same rows this block just staged -> L2-warm; saves the
    // scattered f32 mem gather)
    bf16x4 hb = *(const bf16x4*)(Ac + (size_t)trow * KDIM + HDIM + jfirst);
    f32x4 hv;
    hv[0] = bf2f(hb[0]); hv[1] = bf2f(hb[1]); hv[2] = bf2f(hb[2]); hv[3] = bf2f(hb[3]);

    f32x4 o;
#pragma unroll
    for (int jj = 0; jj < 4; jj++) {
      const int j = jfirst + jj;
      f32x4 bt = *(const f32x4*)&btab[4 * j];
      float rr = fast_sigmoid(q[jj][0] + bt[0]);
      float zz = fast_sigmoid(q[jj][1] + bt[1]);
      float nn = fast_tanh(q[jj][2] + bt[2] + rr * (q[jj][3] + bt[3]));
      o[jj] = (1.0f - zz) * nn + zz * hv[jj];
    }
    if (wr) __builtin_nontemporal_store(o, (f32x4*)&out[(size_t)s * HDIM + jfirst]);
    __syncthreads();
  }
}

// ---------------- launch ----------------

extern "C" void kernel_launch(void* const* d_in, const int* in_sizes, int n_in,
                              void* d_out, int out_size, void* d_ws, size_t ws_size,
                              hipStream_t stream) {
  const float* mem = (const float*)d_in[0];
  const int*   sid = (const int*)d_in[1];
  const float* edu = (const float*)d_in[2];
  const float* Wih = (const float*)d_in[3];
  const float* Whh = (const float*)d_in[4];
  const float* bih = (const float*)d_in[5];
  const float* bhh = (const float*)d_in[6];
  float* out = (float*)d_out;

  char* p = (char*)d_ws;
  unsigned short* Ac  = (unsigned short*)p; p += (size_t)TROWS * KDIM * 2;    // 32 MiB
  unsigned short* Brz = (unsigned short*)p; p += (size_t)2048 * KDIM * 2;     // 8 MiB
  unsigned short* Bn  = (unsigned short*)p; p += (size_t)1024 * KDIM * 2;     // 4 MiB
  int*   lp   = (int*)p;   p += (size_t)SROWS * 4;                            // 256 KiB
  float* btab = (float*)p; p += (size_t)HDIM * 4 * 4;                         // 16 KiB
  unsigned long long* flagb = (unsigned long long*)p; p += (size_t)(SROWS / 64) * 8; // 8 KiB

  hipFuncSetAttribute((const void*)k_gru8, hipFuncAttributeMaxDynamicSharedMemorySize, 2 * BUF);

  hipLaunchKernelGGL(k_init, dim3(SROWS / 256), dim3(256), 0, stream, lp, bih, bhh, btab);
  hipLaunchKernelGGL(k_lp, dim3(TROWS / 256), dim3(256), 0, stream, sid, lp);
  hipLaunchKernelGGL(k_flags, dim3(SROWS / 256), dim3(256), 0, stream, lp, flagb);
  hipLaunchKernelGGL(k_build, dim3(8192 + 3072), dim3(256), 0, stream,
                     edu, mem, sid, Wih, Whh, Ac, Brz, Bn);
  hipLaunchKernelGGL(k_gru8, dim3(1024), dim3(512), 2 * BUF, stream,
                     Ac, Brz, Bn, mem, sid, lp, flagb, btab, out);
}

// Round 20
// 201.273 us; speedup vs baseline: 1.0399x; 1.0399x over previous
//
#include <hip/hip_runtime.h>
#include <hip/hip_bf16.h>
#include <stdint.h>
#include <stddef.h>

typedef short short8 __attribute__((ext_vector_type(8)));
typedef float f32x4 __attribute__((ext_vector_type(4)));

#define SROWS 65536
#define TROWS 8192
#define HDIM  1024
#define KDIM  2048   // concatenated K: [edu | h]
#define NT    32     // K-tiles of 64
#define BUF   40960  // per-buffer LDS: A 16K + Brz 16K + Bn 8K

__device__ __forceinline__ unsigned short f2bf(float f) {
  union { float f; uint32_t u; } v; v.f = f;
  uint32_t u = v.u;
  uint32_t r = (u + 0x7FFFu + ((u >> 16) & 1u)) >> 16;
  return (unsigned short)r;
}

__device__ __forceinline__ float fast_sigmoid(float x) {
  return __builtin_amdgcn_rcpf(1.0f + __builtin_amdgcn_exp2f(-1.44269504f * x));
}
__device__ __forceinline__ float fast_tanh(float x) {
  return 1.0f - 2.0f * __builtin_amdgcn_rcpf(1.0f + __builtin_amdgcn_exp2f(2.88539008f * x));
}

// ---------------- merged prep kernels ----------------

// lp init (65536) + bias table (first 1024 threads)
__global__ __launch_bounds__(256) void k_init(int* lp,
                                              const float* __restrict__ bih,
                                              const float* __restrict__ bhh,
                                              float* __restrict__ btab) {
  int i = blockIdx.x * 256 + threadIdx.x;
  lp[i] = -1;
  if (i < HDIM) {
    btab[4*i+0] = bih[i] + bhh[i];
    btab[4*i+1] = bih[i+HDIM] + bhh[i+HDIM];
    btab[4*i+2] = bih[i+2*HDIM];
    btab[4*i+3] = bhh[i+2*HDIM];
  }
}

__global__ __launch_bounds__(256) void k_lp(const int* __restrict__ sid, int* lp) {
  int i = blockIdx.x * 256 + threadIdx.x;
  if (i < TROWS) atomicMax(&lp[sid[i]], i);
}

// merged build_A (blocks 0..8191) + build_B2 (8192..11263) + flags (11264..11519)
__global__ __launch_bounds__(256) void k_build(const float* __restrict__ edu,
                                               const float* __restrict__ mem,
                                               const int* __restrict__ sid,
                                               const float* __restrict__ Wih,
                                               const float* __restrict__ Whh,
                                               const int* __restrict__ lp,
                                               unsigned short* __restrict__ Ac,
                                               unsigned short* __restrict__ Brz,
                                               unsigned short* __restrict__ Bn,
                                               unsigned long long* __restrict__ flagb) {
  const int b = blockIdx.x;
  if (b < 8192) {
    const int idx = b * 256 + threadIdx.x;
    const int t  = idx >> 8;
    const int k0 = (idx & 255) << 3;
    const float* src;
    if (k0 < HDIM) src = edu + (size_t)t * HDIM + k0;
    else           src = mem + (size_t)sid[t] * HDIM + (k0 - HDIM);
    f32x4 f0 = *(const f32x4*)src;
    f32x4 f1 = *(const f32x4*)(src + 4);
    short8 v;
    v[0]=(short)f2bf(f0[0]); v[1]=(short)f2bf(f0[1]); v[2]=(short)f2bf(f0[2]); v[3]=(short)f2bf(f0[3]);
    v[4]=(short)f2bf(f1[0]); v[5]=(short)f2bf(f1[1]); v[6]=(short)f2bf(f1[2]); v[7]=(short)f2bf(f1[3]);
    *(short8*)(Ac + (size_t)idx * 8) = v;
  } else if (b < 11264) {
    const int idx = (b - 8192) * 256 + threadIdx.x;
    const int c  = idx >> 8;
    const int k0 = (idx & 255) << 3;
    const float* src;
    unsigned short* dst;
    if (c < 2048) {
      const int j = c >> 1, g = c & 1;
      const int row = j + g * 1024;
      src = (k0 < HDIM) ? Wih + (size_t)row * HDIM + k0
                        : Whh + (size_t)row * HDIM + (k0 - HDIM);
      dst = Brz + (size_t)c * KDIM + k0;
    } else {
      const int j = c - 2048;
      src = (k0 < HDIM) ? Wih + (size_t)(j + 2*HDIM) * HDIM + k0
                        : Whh + (size_t)(j + 2*HDIM) * HDIM + (k0 - HDIM);
      dst = Bn + (size_t)j * KDIM + k0;
    }
    f32x4 f0 = *(const f32x4*)src;
    f32x4 f1 = *(const f32x4*)(src + 4);
    short8 v;
    v[0]=(short)f2bf(f0[0]); v[1]=(short)f2bf(f0[1]); v[2]=(short)f2bf(f0[2]); v[3]=(short)f2bf(f0[3]);
    v[4]=(short)f2bf(f1[0]); v[5]=(short)f2bf(f1[1]); v[6]=(short)f2bf(f1[2]); v[7]=(short)f2bf(f1[3]);
    *(short8*)dst = v;
  } else {
    // flags: bit r of flagb[r>>6] = (lp[r] < 0)   (lp complete after k_lp)
    const int i = (b - 11264) * 256 + threadIdx.x;
    unsigned long long m = __ballot(lp[i] < 0);
    if ((threadIdx.x & 63) == 0) flagb[i >> 6] = m;
  }
}

// ---------------- 128x64j dense GEMM, 2 blocks/CU, 2 barriers/tile ----------------
// r17's best-known GEMM, byte-identical: VM(7) ph0 / VM(5) tile-end, XCD-pinned j0,
// (row&7)<<4 swizzle both sides, in-loop copy (X/Y register double-buffer, nt).

#define FENCE() asm volatile("" ::: "memory")
#define BAR()   __builtin_amdgcn_s_barrier()
#define VM(N)   asm volatile("s_waitcnt vmcnt(" #N ")" ::: "memory")

#define STAGE(p0, p1, ldsoff)                                                              \
  __builtin_amdgcn_global_load_lds((const __attribute__((address_space(1))) void*)(p0),   \
      (__attribute__((address_space(3))) void*)(smem + (ldsoff) + w * 1024), 16, 0, 0);    \
  __builtin_amdgcn_global_load_lds((const __attribute__((address_space(1))) void*)(p1),   \
      (__attribute__((address_space(3))) void*)(smem + (ldsoff) + 8192 + w * 1024), 16, 0, 0);

#define STAGE1(p0, ldsoff)                                                                 \
  __builtin_amdgcn_global_load_lds((const __attribute__((address_space(1))) void*)(p0),   \
      (__attribute__((address_space(3))) void*)(smem + (ldsoff) + w * 1024), 16, 0, 0);

#define LDF(base, frag, koff) (*(const short8*)(smem + (base) + (size_t)(frag) * 2048 + (koff)))

#define MF(a, b, c) __builtin_amdgcn_mfma_f32_16x16x32_bf16(a, b, c, 0, 0, 0)

#define MFMA12(ACCN)                                                          \
    acc_rz[0][0] = MF(af[0], bf0, acc_rz[0][0]);                              \
    acc_rz[0][1] = MF(af[0], bf1, acc_rz[0][1]);                              \
    ACCN[0]      = MF(af[0], bf2, ACCN[0]);                                   \
    acc_rz[1][0] = MF(af[1], bf0, acc_rz[1][0]);                              \
    acc_rz[1][1] = MF(af[1], bf1, acc_rz[1][1]);                              \
    ACCN[1]      = MF(af[1], bf2, ACCN[1]);                                   \
    acc_rz[2][0] = MF(af[2], bf0, acc_rz[2][0]);                              \
    acc_rz[2][1] = MF(af[2], bf1, acc_rz[2][1]);                              \
    ACCN[2]      = MF(af[2], bf2, ACCN[2]);                                   \
    acc_rz[3][0] = MF(af[3], bf0, acc_rz[3][0]);                              \
    acc_rz[3][1] = MF(af[3], bf1, acc_rz[3][1]);                              \
    ACCN[3]      = MF(af[3], bf2, ACCN[3]);

#define TILE_BODY(ACCN)                                                       \
  {                                                                           \
    const int cur = t & 1;                                                    \
    const size_t buf = (size_t)cur * BUF, nbuf = (size_t)(cur ^ 1) * BUF;     \
    const size_t abase  = buf + (size_t)wm * 8192;                            \
    const size_t rzbase = buf + 16384 + (size_t)wn * 4096;                    \
    const size_t nbase  = buf + 32768 + (size_t)wn * 2048;                    \
    const int kt1 = (t + 1 < NT) ? t + 1 : NT - 1;                            \
    /* ph0: stage t+1 -> nbuf; retire ONLY stages(t); keep copy loads */      \
    STAGE(pA0 + kt1 * 64, pA1 + kt1 * 64, nbuf);                              \
    STAGE(pRZ0 + kt1 * 64, pRZ1 + kt1 * 64, nbuf + 16384);                    \
    STAGE1(pN + kt1 * 64, nbuf + 32768);                                      \
    VM(7);                                                                    \
    FENCE(); BAR(); FENCE();                                                  \
    {                                                                         \
      short8 bf0 = LDF(rzbase, 0, foff0);                                     \
      short8 bf1 = LDF(rzbase, 1, foff0);                                     \
      short8 bf2 = LDF(nbase,  0, foff0);                                     \
      short8 af[4];                                                           \
      af[0] = LDF(abase, 0, foff0); af[1] = LDF(abase, 1, foff0);             \
      af[2] = LDF(abase, 2, foff0); af[3] = LDF(abase, 3, foff0);             \
      __builtin_amdgcn_s_setprio(1);                                          \
      MFMA12(ACCN)                                                            \
      __builtin_amdgcn_s_setprio(0);                                          \
    }                                                                         \
    /* ph1: compute k1, retire copy-loads(t-1), store them, issue copies(t) */\
    {                                                                         \
      short8 bf0 = LDF(rzbase, 0, foff1);                                     \
      short8 bf1 = LDF(rzbase, 1, foff1);                                     \
      short8 bf2 = LDF(nbase,  0, foff1);                                     \
      short8 af[4];                                                           \
      af[0] = LDF(abase, 0, foff1); af[1] = LDF(abase, 1, foff1);             \
      af[2] = LDF(abase, 2, foff1); af[3] = LDF(abase, 3, foff1);             \
      __builtin_amdgcn_s_setprio(1);                                          \
      MFMA12(ACCN)                                                            \
      __builtin_amdgcn_s_setprio(0);                                          \
    }                                                                         \
    VM(5);                                                                    \
    {                                                                         \
      const int rr = 2 * t + ccp;                                             \
      const bool nv = (fw >> rr) & 1ull;                                      \
      if ((t & 1) == 0) {                                                     \
        if (vY) __builtin_nontemporal_store(cpY, (f32x4*)&out[(size_t)sY * HDIM + ccol]); \
        vX = nv; sX = cbase + rr;                                             \
        if (vX) cpX = __builtin_nontemporal_load((const f32x4*)&mem[(size_t)sX * HDIM + ccol]); \
      } else {                                                                \
        if (vX) __builtin_nontemporal_store(cpX, (f32x4*)&out[(size_t)sX * HDIM + ccol]); \
        vY = nv; sY = cbase + rr;                                             \
        if (vY) cpY = __builtin_nontemporal_load((const f32x4*)&mem[(size_t)sY * HDIM + ccol]); \
      }                                                                       \
    }                                                                         \
    FENCE(); BAR(); FENCE();                                                  \
  }

__global__ __launch_bounds__(512, 4)
void k_gru8(const unsigned short* __restrict__ Ac,
            const unsigned short* __restrict__ Brz,
            const unsigned short* __restrict__ Bn,
            const float* __restrict__ mem,
            const int* __restrict__ sid,
            const int* __restrict__ lp,
            const unsigned long long* __restrict__ flagb,
            const float* __restrict__ btab,
            float* __restrict__ out) {
  extern __shared__ char smem[];

  const int tid  = threadIdx.x;
  const int lane = tid & 63;
  const int w    = tid >> 6;
  const int wm   = w >> 2;        // M half (0..1): 64 rows
  const int wn   = w & 3;         // N quarter (0..3): 16 j's
  const int l15  = lane & 15;
  const int l4   = lane >> 4;

  // XCD-pinned j0 mapping (bijective; B slice 1.5 MB L2-resident per XCD)
  const int bid = blockIdx.x;
  const int t0  = (bid >> 4) * 128;                        // 64 M-panels
  const int j0  = ((bid & 7) * 2 + ((bid >> 3) & 1)) * 64; // 16 J-panels
  const int rz0 = j0 * 2;

  // ---- staging source mapping (inverse (row&7)<<4 swizzle folded in) ----
  const int srow0 = tid >> 3;              // 0..63
  const int scol  = ((tid & 7) * 8) ^ (((tid >> 3) & 7) << 3);

  const unsigned short* pA0  = Ac  + (size_t)(t0 +       srow0) * KDIM + scol;
  const unsigned short* pA1  = Ac  + (size_t)(t0 + 64 +  srow0) * KDIM + scol;
  const unsigned short* pRZ0 = Brz + (size_t)(rz0 +      srow0) * KDIM + scol;
  const unsigned short* pRZ1 = Brz + (size_t)(rz0 + 64 + srow0) * KDIM + scol;
  const unsigned short* pN   = Bn  + (size_t)(j0  +      srow0) * KDIM + scol;

  // ---- fragment read offsets: col_byte ^= (row&7)<<4 ----
  const int rsw = (l15 & 7) << 4;
  const size_t foff0 = (size_t)l15 * 128 + ((l4 * 16)      ^ rsw);
  const size_t foff1 = (size_t)l15 * 128 + ((64 + l4 * 16) ^ rsw);

  f32x4 acc_rz[4][2], acc_nlo[4], acc_nhi[4];
#pragma unroll
  for (int i = 0; i < 4; i++) {
    acc_rz[i][0] = (f32x4){0.f,0.f,0.f,0.f};
    acc_rz[i][1] = (f32x4){0.f,0.f,0.f,0.f};
    acc_nlo[i]   = (f32x4){0.f,0.f,0.f,0.f};
    acc_nhi[i]   = (f32x4){0.f,0.f,0.f,0.f};
  }

  // ---- copy state: 64 rows/block, 2/tile ----
  const int cbase = bid << 6;
  const unsigned long long fw = flagb[bid];
  const int ccp  = tid >> 8;               // 0/1 (wave-uniform)
  const int ccol = (tid & 255) << 2;
  f32x4 cpX, cpY;
  bool  vX = false, vY = false;
  int   sX = 0, sY = 0;

  // ---- prologue: stage tile 0 into buf0, full drain once
  STAGE(pA0, pA1, 0);
  STAGE(pRZ0, pRZ1, 16384);
  STAGE1(pN, 32768);
  VM(0);
  FENCE(); BAR(); FENCE();

  for (int t = 0; t < 16; ++t) TILE_BODY(acc_nlo)     // k < 1024: i_n
  for (int t = 16; t < NT; ++t) TILE_BODY(acc_nhi)    // k >= 1024: h_n

  // ---- drain: final copy store (t=31 odd -> set Y pending), then epilogue
  VM(0);
  if (vY) __builtin_nontemporal_store(cpY, (f32x4*)&out[(size_t)sY * HDIM + ccol]);
  __syncthreads();
  float* epi = (float*)smem;   // [8 waves][16 rows][68]
  const int jfirst = j0 + wn * 16 + l4 * 4;

#pragma unroll
  for (int mf = 0; mf < 4; mf++) {
#pragma unroll
    for (int f = 0; f < 2; f++)
#pragma unroll
      for (int r = 0; r < 4; r++)
        epi[w * 1088 + (l4 * 4 + r) * 68 + (f * 8 + (l15 >> 1)) * 4 + (l15 & 1)] = acc_rz[mf][f][r];
#pragma unroll
    for (int r = 0; r < 4; r++) {
      epi[w * 1088 + (l4 * 4 + r) * 68 + l15 * 4 + 2] = acc_nlo[mf][r];
      epi[w * 1088 + (l4 * 4 + r) * 68 + l15 * 4 + 3] = acc_nhi[mf][r];
    }
    __syncthreads();

    const int trow = t0 + wm * 64 + mf * 16 + l15;
    const int s    = sid[trow];
    const bool wr  = (lp[s] == trow);

    f32x4 q[4];
#pragma unroll
    for (int jj = 0; jj < 4; jj++)
      q[jj] = *(const f32x4*)&epi[w * 1088 + l15 * 68 + l4 * 16 + jj * 4];

    f32x4 hv = *(const f32x4*)&mem[(size_t)s * HDIM + jfirst];
    f32x4 o;
#pragma unroll
    for (int jj = 0; jj < 4; jj++) {
      const int j = jfirst + jj;
      f32x4 bt = *(const f32x4*)&btab[4 * j];
      float rr = fast_sigmoid(q[jj][0] + bt[0]);
      float zz = fast_sigmoid(q[jj][1] + bt[1]);
      float nn = fast_tanh(q[jj][2] + bt[2] + rr * (q[jj][3] + bt[3]));
      o[jj] = (1.0f - zz) * nn + zz * hv[jj];
    }
    if (wr) __builtin_nontemporal_store(o, (f32x4*)&out[(size_t)s * HDIM + jfirst]);
    __syncthreads();
  }
}

// ---------------- launch ----------------

extern "C" void kernel_launch(void* const* d_in, const int* in_sizes, int n_in,
                              void* d_out, int out_size, void* d_ws, size_t ws_size,
                              hipStream_t stream) {
  const float* mem = (const float*)d_in[0];
  const int*   sid = (const int*)d_in[1];
  const float* edu = (const float*)d_in[2];
  const float* Wih = (const float*)d_in[3];
  const float* Whh = (const float*)d_in[4];
  const float* bih = (const float*)d_in[5];
  const float* bhh = (const float*)d_in[6];
  float* out = (float*)d_out;

  char* p = (char*)d_ws;
  unsigned short* Ac  = (unsigned short*)p; p += (size_t)TROWS * KDIM * 2;    // 32 MiB
  unsigned short* Brz = (unsigned short*)p; p += (size_t)2048 * KDIM * 2;     // 8 MiB
  unsigned short* Bn  = (unsigned short*)p; p += (size_t)1024 * KDIM * 2;     // 4 MiB
  int*   lp   = (int*)p;   p += (size_t)SROWS * 4;                            // 256 KiB
  float* btab = (float*)p; p += (size_t)HDIM * 4 * 4;                         // 16 KiB
  unsigned long long* flagb = (unsigned long long*)p; p += (size_t)(SROWS / 64) * 8; // 8 KiB

  hipFuncSetAttribute((const void*)k_gru8, hipFuncAttributeMaxDynamicSharedMemorySize, 2 * BUF);

  hipLaunchKernelGGL(k_init, dim3(SROWS / 256), dim3(256), 0, stream, lp, bih, bhh, btab);
  hipLaunchKernelGGL(k_lp, dim3(TROWS / 256), dim3(256), 0, stream, sid, lp);
  hipLaunchKernelGGL(k_build, dim3(8192 + 3072 + 256), dim3(256), 0, stream,
                     edu, mem, sid, Wih, Whh, lp, Ac, Brz, Bn, flagb);
  hipLaunchKernelGGL(k_gru8, dim3(1024), dim3(512), 2 * BUF, stream,
                     Ac, Brz, Bn, mem, sid, lp, flagb, btab, out);
}